// Round 1
// baseline (735.698 us; speedup 1.0000x reference)
//
#include <hip/hip_runtime.h>
#include <cfloat>
#include <cmath>

// Problem constants
#define H  1024
#define V  50257
#define L  128
#define NB8 ((V + 7) / 8)          // 6283 blocks for logits GEMV (8 rows/block)

// ws layout (float offsets). Total ~79.6K floats (~318 KB).
#define WS_COMB_IN 0                       // embedded[1024] ++ attn_applied[1024]
#define WS_X       2048                    // relu(comb) [1024]
#define WS_H       3072                    // h_new [1024]
#define WS_ATTN    4096                    // raw attention scores [128]
#define WS_LOGITS  4224                    // logits [V], padded to 50260
#define WS_PM      (WS_LOGITS + 50260)     // per-block max, padded 12568
#define WS_PS      (WS_PM + 12568)         // per-block sumexp, padded 12568
#define WS_LS      (WS_PS + 12568)         // scalar logsumexp
#define WS_CTR     (WS_LS + 1)             // atomic completion counter (as uint)

__device__ __forceinline__ float dot4(float4 a, float4 b) {
    return a.x * b.x + a.y * b.y + a.z * b.z + a.w * b.w;
}

__device__ __forceinline__ float wave_sum(float acc) {
    #pragma unroll
    for (int off = 32; off > 0; off >>= 1) acc += __shfl_down(acc, off);
    return acc;
}

__device__ __forceinline__ float sigmoidf(float x) {
    return 1.f / (1.f + expf(-x));
}

// K1: raw attention scores. 32 blocks x 256 (wave per row, 4 rows/block).
// score[l] = attn_W[l][0:H] . emb[token] + attn_W[l][H:2H] . h0 + attn_b[l]
// Block 0 additionally copies embedded -> ws COMB_IN and zeroes the logits counter.
__global__ __launch_bounds__(256) void k_scores(const int* __restrict__ tokens,
                                                const float* __restrict__ h0,
                                                const float* __restrict__ emb,
                                                const float* __restrict__ attn_W,
                                                const float* __restrict__ attn_b,
                                                float* __restrict__ ws) {
    const int wave = threadIdx.x >> 6, lane = threadIdx.x & 63;
    const int l = blockIdx.x * 4 + wave;
    const int token = tokens[0];
    const float4* erow = (const float4*)(emb + (size_t)token * H);
    const float4* hv   = (const float4*)h0;
    const float4* wrow = (const float4*)(attn_W + (size_t)l * (2 * H));
    float acc = 0.f;
    #pragma unroll
    for (int it = 0; it < 4; ++it) acc += dot4(wrow[lane + it * 64], erow[lane + it * 64]);
    #pragma unroll
    for (int it = 0; it < 4; ++it) acc += dot4(wrow[256 + lane + it * 64], hv[lane + it * 64]);
    acc = wave_sum(acc);
    if (lane == 0) ws[WS_ATTN + l] = acc + attn_b[l];
    if (blockIdx.x == 0) {
        // embedded half of comb_in (256 threads x float4 = 1024 floats)
        ((float4*)(ws + WS_COMB_IN))[threadIdx.x] = erow[threadIdx.x];
        if (threadIdx.x == 0) *((unsigned*)(ws + WS_CTR)) = 0u;
    }
}

// K2: softmax (redundant per block) + attn_applied = w @ enc. 4 blocks x 256.
__global__ __launch_bounds__(256) void k_attn_apply(const float* __restrict__ enc,
                                                    float* __restrict__ ws,
                                                    float* __restrict__ dout) {
    __shared__ float w[L];
    const int tid = threadIdx.x;
    if (tid < 64) {
        float s0 = ws[WS_ATTN + tid], s1 = ws[WS_ATTN + 64 + tid];
        float m = fmaxf(s0, s1);
        #pragma unroll
        for (int off = 1; off < 64; off <<= 1) m = fmaxf(m, __shfl_xor(m, off));
        float e0 = expf(s0 - m), e1 = expf(s1 - m);
        float s = e0 + e1;
        #pragma unroll
        for (int off = 1; off < 64; off <<= 1) s += __shfl_xor(s, off);
        float inv = 1.f / s;
        float w0 = e0 * inv, w1 = e1 * inv;
        w[tid]      = w0;
        w[tid + 64] = w1;
        if (blockIdx.x == 0) {
            dout[V + 2 * H + tid]      = w0;   // attn_weights output
            dout[V + 2 * H + 64 + tid] = w1;
        }
    }
    __syncthreads();
    const int j = blockIdx.x * 256 + tid;
    float a = 0.f;
    #pragma unroll 8
    for (int l = 0; l < L; ++l) a += w[l] * enc[l * H + j];
    ws[WS_COMB_IN + H + j] = a;
}

// K3: x = relu(comb_W @ comb_in + comb_b). 256 blocks x 256 (wave per row).
__global__ __launch_bounds__(256) void k_comb(const float* __restrict__ comb_W,
                                              const float* __restrict__ comb_b,
                                              float* __restrict__ ws) {
    const int wave = threadIdx.x >> 6, lane = threadIdx.x & 63;
    const int r = blockIdx.x * 4 + wave;
    const float4* wrow = (const float4*)(comb_W + (size_t)r * (2 * H));
    const float4* cin  = (const float4*)(ws + WS_COMB_IN);
    float acc = 0.f;
    #pragma unroll
    for (int it = 0; it < 8; ++it) acc += dot4(wrow[lane + it * 64], cin[lane + it * 64]);
    acc = wave_sum(acc);
    if (lane == 0) ws[WS_X + r] = fmaxf(acc + comb_b[r], 0.f);
}

// K4: LSTM cell. 1024 blocks x 256; block k computes gate rows {k, k+1024, k+2048, k+3072}.
__global__ __launch_bounds__(256) void k_lstm(const float* __restrict__ W_ih,
                                              const float* __restrict__ W_hh,
                                              const float* __restrict__ b_ih,
                                              const float* __restrict__ b_hh,
                                              const float* __restrict__ h0,
                                              const float* __restrict__ c0,
                                              float* __restrict__ ws,
                                              float* __restrict__ dout) {
    __shared__ float g[4];
    const int wave = threadIdx.x >> 6, lane = threadIdx.x & 63;
    const int k = blockIdx.x;
    const int row = wave * H + k;
    const float4* wi = (const float4*)(W_ih + (size_t)row * H);
    const float4* wh = (const float4*)(W_hh + (size_t)row * H);
    const float4* xv = (const float4*)(ws + WS_X);
    const float4* hv = (const float4*)h0;
    float acc = 0.f;
    #pragma unroll
    for (int it = 0; it < 4; ++it) {
        acc += dot4(wi[lane + it * 64], xv[lane + it * 64]);
        acc += dot4(wh[lane + it * 64], hv[lane + it * 64]);
    }
    acc = wave_sum(acc);
    if (lane == 0) g[wave] = acc + b_ih[row] + b_hh[row];
    __syncthreads();
    if (threadIdx.x == 0) {
        float gi = sigmoidf(g[0]);
        float gf = sigmoidf(g[1]);
        float gg = tanhf(g[2]);
        float go = sigmoidf(g[3]);
        float cn = gf * c0[k] + gi * gg;
        float hn = go * tanhf(cn);
        dout[V + k]     = hn;   // h_new output
        dout[V + H + k] = cn;   // c_new output
        ws[WS_H + k]    = hn;
    }
}

// K5: logits = out_W @ h_new + out_b, per-block online-softmax partials, and a
// fused last-block-done logsumexp merge (threadfence + atomic counter pattern).
// NB8 blocks x 512 (wave per row, 8 rows/block).
__global__ __launch_bounds__(512) void k_logits(const float* __restrict__ out_W,
                                                const float* __restrict__ out_b,
                                                float* __restrict__ ws) {
    __shared__ float z[8];
    __shared__ float red[16];
    __shared__ int lastFlag;
    const int wave = threadIdx.x >> 6, lane = threadIdx.x & 63;
    const int r = blockIdx.x * 8 + wave;
    float zz = -FLT_MAX;
    if (r < V) {
        const float4* wrow = (const float4*)(out_W + (size_t)r * H);
        const float4* hv   = (const float4*)(ws + WS_H);
        float acc = 0.f;
        #pragma unroll
        for (int it = 0; it < 4; ++it) acc += dot4(wrow[lane + it * 64], hv[lane + it * 64]);
        acc = wave_sum(acc);
        zz = acc + out_b[r];
        if (lane == 0) ws[WS_LOGITS + r] = zz;
    }
    if (lane == 0) z[wave] = zz;
    __syncthreads();
    if (threadIdx.x == 0) {
        float m = -FLT_MAX;
        #pragma unroll
        for (int i = 0; i < 8; ++i) m = fmaxf(m, z[i]);
        float s = 0.f;
        #pragma unroll
        for (int i = 0; i < 8; ++i) s += expf(z[i] - m);
        ws[WS_PM + blockIdx.x] = m;
        ws[WS_PS + blockIdx.x] = s;
        __threadfence();                    // release partials
        unsigned prev = atomicAdd((unsigned*)(ws + WS_CTR), 1u);
        lastFlag = (prev == NB8 - 1);
    }
    __syncthreads();
    if (lastFlag) {
        __threadfence();                    // acquire all partials
        const int tid = threadIdx.x;
        float m = -FLT_MAX;
        for (int i = tid; i < NB8; i += 512) m = fmaxf(m, ws[WS_PM + i]);
        #pragma unroll
        for (int off = 32; off > 0; off >>= 1) m = fmaxf(m, __shfl_xor(m, off));
        if (lane == 0) red[wave] = m;
        __syncthreads();
        float M = red[0];
        #pragma unroll
        for (int i = 1; i < 8; ++i) M = fmaxf(M, red[i]);
        float s = 0.f;
        for (int i = tid; i < NB8; i += 512) s += ws[WS_PS + i] * expf(ws[WS_PM + i] - M);
        #pragma unroll
        for (int off = 32; off > 0; off >>= 1) s += __shfl_xor(s, off);
        if (lane == 0) red[8 + wave] = s;
        __syncthreads();
        if (tid == 0) {
            float S = 0.f;
            #pragma unroll
            for (int i = 0; i < 8; ++i) S += red[8 + i];
            ws[WS_LS] = M + logf(S);
        }
    }
}

// K6: out[v] = logits[v] - logsumexp.
__global__ __launch_bounds__(256) void k_lsm(const float* __restrict__ ws,
                                             float* __restrict__ dout) {
    const int v = blockIdx.x * 256 + threadIdx.x;
    if (v < V) dout[v] = ws[WS_LOGITS + v] - ws[WS_LS];
}

extern "C" void kernel_launch(void* const* d_in, const int* in_sizes, int n_in,
                              void* d_out, int out_size, void* d_ws, size_t ws_size,
                              hipStream_t stream) {
    const int*   tokens = (const int*)  d_in[0];
    const float* h0     = (const float*)d_in[1];
    const float* c0     = (const float*)d_in[2];
    const float* enc    = (const float*)d_in[3];
    const float* emb    = (const float*)d_in[4];
    const float* attn_W = (const float*)d_in[5];
    const float* attn_b = (const float*)d_in[6];
    const float* comb_W = (const float*)d_in[7];
    const float* comb_b = (const float*)d_in[8];
    const float* W_ih   = (const float*)d_in[9];
    const float* W_hh   = (const float*)d_in[10];
    const float* b_ih   = (const float*)d_in[11];
    const float* b_hh   = (const float*)d_in[12];
    const float* out_W  = (const float*)d_in[13];
    const float* out_b  = (const float*)d_in[14];
    float* dout = (float*)d_out;
    float* ws   = (float*)d_ws;

    k_scores<<<32, 256, 0, stream>>>(tokens, h0, emb, attn_W, attn_b, ws);
    k_attn_apply<<<4, 256, 0, stream>>>(enc, ws, dout);
    k_comb<<<256, 256, 0, stream>>>(comb_W, comb_b, ws);
    k_lstm<<<H, 256, 0, stream>>>(W_ih, W_hh, b_ih, b_hh, h0, c0, ws, dout);
    k_logits<<<NB8, 512, 0, stream>>>(out_W, out_b, ws);
    k_lsm<<<(V + 255) / 256, 256, 0, stream>>>(ws, dout);
}

// Round 2
// 431.468 us; speedup vs baseline: 1.7051x; 1.7051x over previous
//
#include <hip/hip_runtime.h>
#include <cfloat>
#include <cmath>

// Problem constants
#define H  1024
#define V  50257
#define L  128
#define NB4 ((V + 3) / 4)          // 12565 blocks for logits GEMV (4 rows/block)

// ws layout (float offsets). Total ~79.6K floats (~318 KB).
#define WS_COMB_IN 0                       // embedded[1024] ++ attn_applied[1024]
#define WS_X       2048                    // relu(comb) [1024]
#define WS_H       3072                    // h_new [1024]
#define WS_ATTN    4096                    // raw attention scores [128]
#define WS_LOGITS  4224                    // logits [V], padded to 50260
#define WS_PM      (WS_LOGITS + 50260)     // per-block max [NB4], padded 12568
#define WS_PS      (WS_PM + 12568)         // per-block sumexp [NB4], padded 12568

__device__ __forceinline__ float dot4(float4 a, float4 b) {
    return a.x * b.x + a.y * b.y + a.z * b.z + a.w * b.w;
}

__device__ __forceinline__ float wave_sum(float acc) {
    #pragma unroll
    for (int off = 32; off > 0; off >>= 1) acc += __shfl_down(acc, off);
    return acc;
}

__device__ __forceinline__ float sigmoidf(float x) {
    return 1.f / (1.f + expf(-x));
}

// K1: raw attention scores. 32 blocks x 256 (wave per row, 4 rows/block).
// score[l] = attn_W[l][0:H] . emb[token] + attn_W[l][H:2H] . h0 + attn_b[l]
// Block 0 additionally copies embedded -> ws COMB_IN.
__global__ __launch_bounds__(256) void k_scores(const int* __restrict__ tokens,
                                                const float* __restrict__ h0,
                                                const float* __restrict__ emb,
                                                const float* __restrict__ attn_W,
                                                const float* __restrict__ attn_b,
                                                float* __restrict__ ws) {
    const int wave = threadIdx.x >> 6, lane = threadIdx.x & 63;
    const int l = blockIdx.x * 4 + wave;
    const int token = tokens[0];
    const float4* erow = (const float4*)(emb + (size_t)token * H);
    const float4* hv   = (const float4*)h0;
    const float4* wrow = (const float4*)(attn_W + (size_t)l * (2 * H));
    float acc = 0.f;
    #pragma unroll
    for (int it = 0; it < 4; ++it) acc += dot4(wrow[lane + it * 64], erow[lane + it * 64]);
    #pragma unroll
    for (int it = 0; it < 4; ++it) acc += dot4(wrow[256 + lane + it * 64], hv[lane + it * 64]);
    acc = wave_sum(acc);
    if (lane == 0) ws[WS_ATTN + l] = acc + attn_b[l];
    if (blockIdx.x == 0) {
        // embedded half of comb_in (256 threads x float4 = 1024 floats)
        ((float4*)(ws + WS_COMB_IN))[threadIdx.x] = erow[threadIdx.x];
    }
}

// K2: softmax (redundant per block) + attn_applied = w @ enc. 4 blocks x 256.
__global__ __launch_bounds__(256) void k_attn_apply(const float* __restrict__ enc,
                                                    float* __restrict__ ws,
                                                    float* __restrict__ dout) {
    __shared__ float w[L];
    const int tid = threadIdx.x;
    if (tid < 64) {
        float s0 = ws[WS_ATTN + tid], s1 = ws[WS_ATTN + 64 + tid];
        float m = fmaxf(s0, s1);
        #pragma unroll
        for (int off = 1; off < 64; off <<= 1) m = fmaxf(m, __shfl_xor(m, off));
        float e0 = expf(s0 - m), e1 = expf(s1 - m);
        float s = e0 + e1;
        #pragma unroll
        for (int off = 1; off < 64; off <<= 1) s += __shfl_xor(s, off);
        float inv = 1.f / s;
        float w0 = e0 * inv, w1 = e1 * inv;
        w[tid]      = w0;
        w[tid + 64] = w1;
        if (blockIdx.x == 0) {
            dout[V + 2 * H + tid]      = w0;   // attn_weights output
            dout[V + 2 * H + 64 + tid] = w1;
        }
    }
    __syncthreads();
    const int j = blockIdx.x * 256 + tid;
    float a = 0.f;
    #pragma unroll 8
    for (int l = 0; l < L; ++l) a += w[l] * enc[l * H + j];
    ws[WS_COMB_IN + H + j] = a;
}

// K3: x = relu(comb_W @ comb_in + comb_b). 256 blocks x 256 (wave per row).
__global__ __launch_bounds__(256) void k_comb(const float* __restrict__ comb_W,
                                              const float* __restrict__ comb_b,
                                              float* __restrict__ ws) {
    const int wave = threadIdx.x >> 6, lane = threadIdx.x & 63;
    const int r = blockIdx.x * 4 + wave;
    const float4* wrow = (const float4*)(comb_W + (size_t)r * (2 * H));
    const float4* cin  = (const float4*)(ws + WS_COMB_IN);
    float acc = 0.f;
    #pragma unroll
    for (int it = 0; it < 8; ++it) acc += dot4(wrow[lane + it * 64], cin[lane + it * 64]);
    acc = wave_sum(acc);
    if (lane == 0) ws[WS_X + r] = fmaxf(acc + comb_b[r], 0.f);
}

// K4: LSTM cell. 1024 blocks x 256; block k computes gate rows {k, k+1024, k+2048, k+3072}.
__global__ __launch_bounds__(256) void k_lstm(const float* __restrict__ W_ih,
                                              const float* __restrict__ W_hh,
                                              const float* __restrict__ b_ih,
                                              const float* __restrict__ b_hh,
                                              const float* __restrict__ h0,
                                              const float* __restrict__ c0,
                                              float* __restrict__ ws,
                                              float* __restrict__ dout) {
    __shared__ float g[4];
    const int wave = threadIdx.x >> 6, lane = threadIdx.x & 63;
    const int k = blockIdx.x;
    const int row = wave * H + k;
    const float4* wi = (const float4*)(W_ih + (size_t)row * H);
    const float4* wh = (const float4*)(W_hh + (size_t)row * H);
    const float4* xv = (const float4*)(ws + WS_X);
    const float4* hv = (const float4*)h0;
    float acc = 0.f;
    #pragma unroll
    for (int it = 0; it < 4; ++it) {
        acc += dot4(wi[lane + it * 64], xv[lane + it * 64]);
        acc += dot4(wh[lane + it * 64], hv[lane + it * 64]);
    }
    acc = wave_sum(acc);
    if (lane == 0) g[wave] = acc + b_ih[row] + b_hh[row];
    __syncthreads();
    if (threadIdx.x == 0) {
        float gi = sigmoidf(g[0]);
        float gf = sigmoidf(g[1]);
        float gg = tanhf(g[2]);
        float go = sigmoidf(g[3]);
        float cn = gf * c0[k] + gi * gg;
        float hn = go * tanhf(cn);
        dout[V + k]     = hn;   // h_new output
        dout[V + H + k] = cn;   // c_new output
        ws[WS_H + k]    = hn;
    }
}

// K5: logits = out_W @ h_new + out_b, plus per-block online-softmax partials.
// NB4 blocks x 256 (wave per row, 4 rows/block). NO cross-block communication.
__global__ __launch_bounds__(256) void k_logits(const float* __restrict__ out_W,
                                                const float* __restrict__ out_b,
                                                float* __restrict__ ws) {
    __shared__ float z[4];
    const int wave = threadIdx.x >> 6, lane = threadIdx.x & 63;
    const int r = blockIdx.x * 4 + wave;
    float zz = -FLT_MAX;
    if (r < V) {
        const float4* wrow = (const float4*)(out_W + (size_t)r * H);
        const float4* hv   = (const float4*)(ws + WS_H);
        float acc = 0.f;
        #pragma unroll
        for (int it = 0; it < 4; ++it) acc += dot4(wrow[lane + it * 64], hv[lane + it * 64]);
        acc = wave_sum(acc);
        zz = acc + out_b[r];
        if (lane == 0) ws[WS_LOGITS + r] = zz;
    }
    if (lane == 0) z[wave] = zz;
    __syncthreads();
    if (threadIdx.x == 0) {
        float m = fmaxf(fmaxf(z[0], z[1]), fmaxf(z[2], z[3]));
        float s = expf(z[0] - m) + expf(z[1] - m) + expf(z[2] - m) + expf(z[3] - m);
        ws[WS_PM + blockIdx.x] = m;
        ws[WS_PS + blockIdx.x] = s;
    }
}

// K6: out[v] = logits[v] - logsumexp, with the logsumexp redundantly recomputed
// per block from the (L2/L3-resident, ~100 KB) partial arrays. 50 blocks x 1024.
// Every block computes the bit-identical reduction; no cross-block traffic.
__global__ __launch_bounds__(1024) void k_lsm(const float* __restrict__ ws,
                                              float* __restrict__ dout) {
    __shared__ float red[16];
    const int tid = threadIdx.x;
    const int wave = tid >> 6, lane = tid & 63;
    float m = -FLT_MAX;
    for (int i = tid; i < NB4; i += 1024) m = fmaxf(m, ws[WS_PM + i]);
    #pragma unroll
    for (int off = 32; off > 0; off >>= 1) m = fmaxf(m, __shfl_xor(m, off));
    if (lane == 0) red[wave] = m;
    __syncthreads();
    float M = red[0];
    #pragma unroll
    for (int i = 1; i < 16; ++i) M = fmaxf(M, red[i]);
    __syncthreads();
    float s = 0.f;
    for (int i = tid; i < NB4; i += 1024) s += ws[WS_PS + i] * expf(ws[WS_PM + i] - M);
    #pragma unroll
    for (int off = 32; off > 0; off >>= 1) s += __shfl_xor(s, off);
    if (lane == 0) red[wave] = s;
    __syncthreads();
    float S = 0.f;
    #pragma unroll
    for (int i = 0; i < 16; ++i) S += red[i];
    const float LS = M + logf(S);
    const int v = blockIdx.x * 1024 + tid;
    if (v < V) dout[v] = ws[WS_LOGITS + v] - LS;
}

extern "C" void kernel_launch(void* const* d_in, const int* in_sizes, int n_in,
                              void* d_out, int out_size, void* d_ws, size_t ws_size,
                              hipStream_t stream) {
    const int*   tokens = (const int*)  d_in[0];
    const float* h0     = (const float*)d_in[1];
    const float* c0     = (const float*)d_in[2];
    const float* enc    = (const float*)d_in[3];
    const float* emb    = (const float*)d_in[4];
    const float* attn_W = (const float*)d_in[5];
    const float* attn_b = (const float*)d_in[6];
    const float* comb_W = (const float*)d_in[7];
    const float* comb_b = (const float*)d_in[8];
    const float* W_ih   = (const float*)d_in[9];
    const float* W_hh   = (const float*)d_in[10];
    const float* b_ih   = (const float*)d_in[11];
    const float* b_hh   = (const float*)d_in[12];
    const float* out_W  = (const float*)d_in[13];
    const float* out_b  = (const float*)d_in[14];
    float* dout = (float*)d_out;
    float* ws   = (float*)d_ws;

    k_scores<<<32, 256, 0, stream>>>(tokens, h0, emb, attn_W, attn_b, ws);
    k_attn_apply<<<4, 256, 0, stream>>>(enc, ws, dout);
    k_comb<<<256, 256, 0, stream>>>(comb_W, comb_b, ws);
    k_lstm<<<H, 256, 0, stream>>>(W_ih, W_hh, b_ih, b_hh, h0, c0, ws, dout);
    k_logits<<<NB4, 256, 0, stream>>>(out_W, out_b, ws);
    k_lsm<<<(V + 1023) / 1024, 1024, 0, stream>>>(ws, dout);
}

// Round 3
// 430.958 us; speedup vs baseline: 1.7071x; 1.0012x over previous
//
#include <hip/hip_runtime.h>
#include <cfloat>
#include <cmath>

// Problem constants
#define H  1024
#define V  50257
#define L  128
#define NB8 ((V + 7) / 8)          // 6283 blocks for logits GEMV (8 rows/block, 2/wave)

// ws layout (float offsets). Total ~79.6K floats (~318 KB).
#define WS_COMB_IN 0                       // embedded[1024] ++ attn_applied[1024]
#define WS_X       2048                    // relu(comb) [1024]
#define WS_H       3072                    // h_new [1024]
#define WS_ATTN    4096                    // raw attention scores [128]
#define WS_LOGITS  4224                    // logits [V], padded to 50260
#define WS_PM      (WS_LOGITS + 50260)     // per-block max [NB8], padded 12568
#define WS_PS      (WS_PM + 12568)         // per-block sumexp [NB8], padded 12568

__device__ __forceinline__ float dot4(float4 a, float4 b) {
    return a.x * b.x + a.y * b.y + a.z * b.z + a.w * b.w;
}

__device__ __forceinline__ float wave_sum(float acc) {
    #pragma unroll
    for (int off = 32; off > 0; off >>= 1) acc += __shfl_down(acc, off);
    return acc;
}

__device__ __forceinline__ float sigmoidf(float x) {
    return 1.f / (1.f + expf(-x));
}

// K1: raw attention scores. 32 blocks x 256 (wave per row, 4 rows/block).
// score[l] = attn_W[l][0:H] . emb[token] + attn_W[l][H:2H] . h0 + attn_b[l]
// Block 0 additionally copies embedded -> ws COMB_IN.
__global__ __launch_bounds__(256) void k_scores(const int* __restrict__ tokens,
                                                const float* __restrict__ h0,
                                                const float* __restrict__ emb,
                                                const float* __restrict__ attn_W,
                                                const float* __restrict__ attn_b,
                                                float* __restrict__ ws) {
    const int wave = threadIdx.x >> 6, lane = threadIdx.x & 63;
    const int l = blockIdx.x * 4 + wave;
    const int token = tokens[0];
    const float4* erow = (const float4*)(emb + (size_t)token * H);
    const float4* hv   = (const float4*)h0;
    const float4* wrow = (const float4*)(attn_W + (size_t)l * (2 * H));
    float acc = 0.f;
    #pragma unroll
    for (int it = 0; it < 4; ++it) acc += dot4(wrow[lane + it * 64], erow[lane + it * 64]);
    #pragma unroll
    for (int it = 0; it < 4; ++it) acc += dot4(wrow[256 + lane + it * 64], hv[lane + it * 64]);
    acc = wave_sum(acc);
    if (lane == 0) ws[WS_ATTN + l] = acc + attn_b[l];
    if (blockIdx.x == 0) {
        // embedded half of comb_in (256 threads x float4 = 1024 floats)
        ((float4*)(ws + WS_COMB_IN))[threadIdx.x] = erow[threadIdx.x];
    }
}

// K2: softmax (redundant per block) + attn_applied = w @ enc. 4 blocks x 256.
__global__ __launch_bounds__(256) void k_attn_apply(const float* __restrict__ enc,
                                                    float* __restrict__ ws,
                                                    float* __restrict__ dout) {
    __shared__ float w[L];
    const int tid = threadIdx.x;
    if (tid < 64) {
        float s0 = ws[WS_ATTN + tid], s1 = ws[WS_ATTN + 64 + tid];
        float m = fmaxf(s0, s1);
        #pragma unroll
        for (int off = 1; off < 64; off <<= 1) m = fmaxf(m, __shfl_xor(m, off));
        float e0 = expf(s0 - m), e1 = expf(s1 - m);
        float s = e0 + e1;
        #pragma unroll
        for (int off = 1; off < 64; off <<= 1) s += __shfl_xor(s, off);
        float inv = 1.f / s;
        float w0 = e0 * inv, w1 = e1 * inv;
        w[tid]      = w0;
        w[tid + 64] = w1;
        if (blockIdx.x == 0) {
            dout[V + 2 * H + tid]      = w0;   // attn_weights output
            dout[V + 2 * H + 64 + tid] = w1;
        }
    }
    __syncthreads();
    const int j = blockIdx.x * 256 + tid;
    float a = 0.f;
    #pragma unroll 8
    for (int l = 0; l < L; ++l) a += w[l] * enc[l * H + j];
    ws[WS_COMB_IN + H + j] = a;
}

// K3: x = relu(comb_W @ comb_in + comb_b). 256 blocks x 256 (wave per row).
__global__ __launch_bounds__(256) void k_comb(const float* __restrict__ comb_W,
                                              const float* __restrict__ comb_b,
                                              float* __restrict__ ws) {
    const int wave = threadIdx.x >> 6, lane = threadIdx.x & 63;
    const int r = blockIdx.x * 4 + wave;
    const float4* wrow = (const float4*)(comb_W + (size_t)r * (2 * H));
    const float4* cin  = (const float4*)(ws + WS_COMB_IN);
    float acc = 0.f;
    #pragma unroll
    for (int it = 0; it < 8; ++it) acc += dot4(wrow[lane + it * 64], cin[lane + it * 64]);
    acc = wave_sum(acc);
    if (lane == 0) ws[WS_X + r] = fmaxf(acc + comb_b[r], 0.f);
}

// K4: LSTM cell. 1024 blocks x 256; block k computes gate rows {k, k+1024, k+2048, k+3072}.
__global__ __launch_bounds__(256) void k_lstm(const float* __restrict__ W_ih,
                                              const float* __restrict__ W_hh,
                                              const float* __restrict__ b_ih,
                                              const float* __restrict__ b_hh,
                                              const float* __restrict__ h0,
                                              const float* __restrict__ c0,
                                              float* __restrict__ ws,
                                              float* __restrict__ dout) {
    __shared__ float g[4];
    const int wave = threadIdx.x >> 6, lane = threadIdx.x & 63;
    const int k = blockIdx.x;
    const int row = wave * H + k;
    const float4* wi = (const float4*)(W_ih + (size_t)row * H);
    const float4* wh = (const float4*)(W_hh + (size_t)row * H);
    const float4* xv = (const float4*)(ws + WS_X);
    const float4* hv = (const float4*)h0;
    float acc = 0.f;
    #pragma unroll
    for (int it = 0; it < 4; ++it) {
        acc += dot4(wi[lane + it * 64], xv[lane + it * 64]);
        acc += dot4(wh[lane + it * 64], hv[lane + it * 64]);
    }
    acc = wave_sum(acc);
    if (lane == 0) g[wave] = acc + b_ih[row] + b_hh[row];
    __syncthreads();
    if (threadIdx.x == 0) {
        float gi = sigmoidf(g[0]);
        float gf = sigmoidf(g[1]);
        float gg = tanhf(g[2]);
        float go = sigmoidf(g[3]);
        float cn = gf * c0[k] + gi * gg;
        float hn = go * tanhf(cn);
        dout[V + k]     = hn;   // h_new output
        dout[V + H + k] = cn;   // c_new output
        ws[WS_H + k]    = hn;
    }
}

// K5: logits = out_W @ h_new + out_b, plus per-block online-softmax partials.
// NB8 blocks x 256; each wave computes TWO consecutive rows (8 rows/block),
// sharing the h_new register loads between both rows. No cross-block traffic.
__global__ __launch_bounds__(256) void k_logits(const float* __restrict__ out_W,
                                                const float* __restrict__ out_b,
                                                float* __restrict__ ws) {
    __shared__ float z[8];
    const int wave = threadIdx.x >> 6, lane = threadIdx.x & 63;
    const int r0 = blockIdx.x * 8 + wave * 2;
    const int r1 = r0 + 1;
    const float4* hv = (const float4*)(ws + WS_H);
    float4 h0v = hv[lane];
    float4 h1v = hv[lane + 64];
    float4 h2v = hv[lane + 128];
    float4 h3v = hv[lane + 192];
    float acc0 = 0.f, acc1 = 0.f;
    if (r0 < V) {
        const float4* w0 = (const float4*)(out_W + (size_t)r0 * H);
        acc0 = dot4(w0[lane], h0v) + dot4(w0[lane + 64], h1v)
             + dot4(w0[lane + 128], h2v) + dot4(w0[lane + 192], h3v);
    }
    if (r1 < V) {
        const float4* w1 = (const float4*)(out_W + (size_t)r1 * H);
        acc1 = dot4(w1[lane], h0v) + dot4(w1[lane + 64], h1v)
             + dot4(w1[lane + 128], h2v) + dot4(w1[lane + 192], h3v);
    }
    acc0 = wave_sum(acc0);
    acc1 = wave_sum(acc1);
    float z0 = -FLT_MAX, z1 = -FLT_MAX;
    if (lane == 0) {
        if (r0 < V) { z0 = acc0 + out_b[r0]; ws[WS_LOGITS + r0] = z0; }
        if (r1 < V) { z1 = acc1 + out_b[r1]; ws[WS_LOGITS + r1] = z1; }
        z[wave * 2]     = z0;
        z[wave * 2 + 1] = z1;
    }
    __syncthreads();
    if (threadIdx.x == 0) {
        float m = -FLT_MAX;
        #pragma unroll
        for (int i = 0; i < 8; ++i) m = fmaxf(m, z[i]);
        float s = 0.f;
        #pragma unroll
        for (int i = 0; i < 8; ++i) s += expf(z[i] - m);
        ws[WS_PM + blockIdx.x] = m;
        ws[WS_PS + blockIdx.x] = s;
    }
}

// K6: out[v] = logits[v] - logsumexp, with the logsumexp redundantly recomputed
// per block from the (L2/L3-resident, ~50 KB) partial arrays. 50 blocks x 1024.
// Every block computes the bit-identical reduction; no cross-block traffic.
__global__ __launch_bounds__(1024) void k_lsm(const float* __restrict__ ws,
                                              float* __restrict__ dout) {
    __shared__ float red[16];
    const int tid = threadIdx.x;
    const int wave = tid >> 6, lane = tid & 63;
    float m = -FLT_MAX;
    for (int i = tid; i < NB8; i += 1024) m = fmaxf(m, ws[WS_PM + i]);
    #pragma unroll
    for (int off = 32; off > 0; off >>= 1) m = fmaxf(m, __shfl_xor(m, off));
    if (lane == 0) red[wave] = m;
    __syncthreads();
    float M = red[0];
    #pragma unroll
    for (int i = 1; i < 16; ++i) M = fmaxf(M, red[i]);
    __syncthreads();
    float s = 0.f;
    for (int i = tid; i < NB8; i += 1024) s += ws[WS_PS + i] * expf(ws[WS_PM + i] - M);
    #pragma unroll
    for (int off = 32; off > 0; off >>= 1) s += __shfl_xor(s, off);
    if (lane == 0) red[wave] = s;
    __syncthreads();
    float S = 0.f;
    #pragma unroll
    for (int i = 0; i < 16; ++i) S += red[i];
    const float LS = M + logf(S);
    const int v = blockIdx.x * 1024 + tid;
    if (v < V) dout[v] = ws[WS_LOGITS + v] - LS;
}

extern "C" void kernel_launch(void* const* d_in, const int* in_sizes, int n_in,
                              void* d_out, int out_size, void* d_ws, size_t ws_size,
                              hipStream_t stream) {
    const int*   tokens = (const int*)  d_in[0];
    const float* h0     = (const float*)d_in[1];
    const float* c0     = (const float*)d_in[2];
    const float* enc    = (const float*)d_in[3];
    const float* emb    = (const float*)d_in[4];
    const float* attn_W = (const float*)d_in[5];
    const float* attn_b = (const float*)d_in[6];
    const float* comb_W = (const float*)d_in[7];
    const float* comb_b = (const float*)d_in[8];
    const float* W_ih   = (const float*)d_in[9];
    const float* W_hh   = (const float*)d_in[10];
    const float* b_ih   = (const float*)d_in[11];
    const float* b_hh   = (const float*)d_in[12];
    const float* out_W  = (const float*)d_in[13];
    const float* out_b  = (const float*)d_in[14];
    float* dout = (float*)d_out;
    float* ws   = (float*)d_ws;

    k_scores<<<32, 256, 0, stream>>>(tokens, h0, emb, attn_W, attn_b, ws);
    k_attn_apply<<<4, 256, 0, stream>>>(enc, ws, dout);
    k_comb<<<256, 256, 0, stream>>>(comb_W, comb_b, ws);
    k_lstm<<<H, 256, 0, stream>>>(W_ih, W_hh, b_ih, b_hh, h0, c0, ws, dout);
    k_logits<<<NB8, 256, 0, stream>>>(out_W, out_b, ws);
    k_lsm<<<(V + 1023) / 1024, 1024, 0, stream>>>(ws, dout);
}